// Round 6
// baseline (151.588 us; speedup 1.0000x reference)
//
#include <hip/hip_runtime.h>
#include <stdint.h>

// Dims: msa[1,S,R,M] fp32 ; left_w/right_w[M,C] ; out_w[C*C,CZ] ; out[1,R,R,CZ] fp32
#define S_DIM 128
#define R_DIM 256
#define M_DIM 256
#define C_DIM 32
#define CZ_DIM 128
#define K2_DIM 1024  // C*C

typedef _Float16 f16;
typedef _Float16 f16x4 __attribute__((ext_vector_type(4)));
typedef _Float16 f16x8 __attribute__((ext_vector_type(8)));
typedef float f32x4 __attribute__((ext_vector_type(4)));
typedef float f32x16 __attribute__((ext_vector_type(16)));

typedef const __attribute__((address_space(1))) uint32_t gu32_t;
typedef __attribute__((address_space(3))) uint32_t lu32_t;
// async 16B global->LDS DMA; LDS dest = wave-uniform base + lane*16 (linear)
#define GLOAD_LDS16(g, l) \
    __builtin_amdgcn_global_load_lds((gu32_t*)(g), (lu32_t*)(l), 16, 0, 0)

// ---------------------------------------------------------------------------
// proj (R1-proven, unchanged)
// ---------------------------------------------------------------------------
__global__ __launch_bounds__(256, 4)
void proj_kernel(const float* __restrict__ msa, const float* __restrict__ lw,
                 const float* __restrict__ rw, const float* __restrict__ ow,
                 f16* __restrict__ left_t, f16* __restrict__ rt2,
                 f16* __restrict__ wt2) {
    __shared__ __align__(16) f16 wlT[8192];  // [mc][c][j] contiguous frag rows
    __shared__ __align__(16) f16 wrT[8192];

    int bid = blockIdx.x;            // 512 = 256 r * 2 s-halves
    int tid = threadIdx.x;
    int w = tid >> 6;
    int lane = tid & 63;
    int q = lane >> 4, li = lane & 15;
    int r  = bid >> 1;
    int s0 = (bid & 1) << 6;
    int s_col = s0 + w * 16 + li;

    const f32x4* bp = (const f32x4*)(msa + ((size_t)s_col * R_DIM + r) * M_DIM + q * 8);
    f32x4 b[16];
#pragma unroll
    for (int ks = 0; ks < 8; ks++) { b[2 * ks] = bp[ks * 8]; b[2 * ks + 1] = bp[ks * 8 + 1]; }

    {
        int i = bid * 256 + tid;     // in [0, CZ*K2)
        int cz = i >> 10, k2 = i & 1023;
        int c = k2 >> 5, e = k2 & 31;
        int k2p = ((e >> 2) << 7) + (c << 2) + (e & 3);
        int ntile = cz >> 5, l31o = cz & 31;
        int kk = k2p >> 4, q5o = (k2p >> 3) & 1, j = k2p & 7;
        wt2[(ntile * 64 + kk) * 512 + (l31o * 2 + q5o) * 8 + j] = (f16)ow[k2 * CZ_DIM + cz];
    }
#pragma unroll
    for (int k = 0; k < 32; k++) {
        int i = k * 256 + tid;       // i = m*32 + c
        int m = i >> 5, c = i & 31;
        int d = ((m >> 3) * 32 + c) * 8 + (m & 7);
        wlT[d] = (f16)lw[i];
        wrT[d] = (f16)rw[i];
    }
    __syncthreads();

    f32x4 aL0 = {0,0,0,0}, aL1 = {0,0,0,0}, aR0 = {0,0,0,0}, aR1 = {0,0,0,0};
#pragma unroll
    for (int ks = 0; ks < 8; ks++) {
        f16x8 bf;
#pragma unroll
        for (int u = 0; u < 4; u++) { bf[u] = (f16)b[2*ks][u]; bf[4 + u] = (f16)b[2*ks+1][u]; }
        const f16* a0 = wlT + ((ks * 4 + q) * 32 + li) * 8;
        const f16* a1 = wrT + ((ks * 4 + q) * 32 + li) * 8;
        f16x8 al0 = *(const f16x8*)(a0);
        f16x8 al1 = *(const f16x8*)(a0 + 128);   // rows li+16
        f16x8 ar0 = *(const f16x8*)(a1);
        f16x8 ar1 = *(const f16x8*)(a1 + 128);
        aL0 = __builtin_amdgcn_mfma_f32_16x16x32_f16(al0, bf, aL0, 0, 0, 0);
        aL1 = __builtin_amdgcn_mfma_f32_16x16x32_f16(al1, bf, aL1, 0, 0, 0);
        aR0 = __builtin_amdgcn_mfma_f32_16x16x32_f16(ar0, bf, aR0, 0, 0, 0);
        aR1 = __builtin_amdgcn_mfma_f32_16x16x32_f16(ar1, bf, aR1, 0, 0, 0);
    }
    int ks_s = s_col >> 4, q5_s = (s_col >> 3) & 1, j_s = s_col & 7;
    int sbase = (r * 8 + ks_s) * 512 + q5_s * 8 + j_s;
    int rl = r & 7;
    f16* Lb = left_t + (size_t)(r >> 3) * 32768;
    int sc = s_col >> 3, sj = s_col & 7;
#pragma unroll
    for (int reg = 0; reg < 4; reg++) {
        int c0 = q * 4 + reg;                    // 0..15 ; row&15 == c0 for both rows
        int row0 = rl * 32 + c0;
        int swz = sc ^ c0;
        Lb[(row0 * 16 + swz) * 8 + sj]        = (f16)aL0[reg];
        Lb[((row0 + 16) * 16 + swz) * 8 + sj] = (f16)aL1[reg];
        rt2[sbase + c0 * 16]        = (f16)aR0[reg];
        rt2[sbase + (c0 + 16) * 16] = (f16)aR1[reg];
    }
}

// ---------------------------------------------------------------------------
// fuse_kernel v10: persistent 1-block/CU co-design. 256 blocks x 512 thr,
// 128KB LDS (Ls left 64K | Pr pair+reduce 64K — NO overlay), 2 waves/SIMD
// -> 256-reg budget. Per block: 8 tiles (fixed bt, br = brq*8+j).
//   - afr loaded ONCE per block (registers survive all 8 tiles)
//   - W chunks 0..7 register-resident (wR, loaded once); chunks 8..31
//     streamed per tile with a lead-3 issue schedule
//   - left(j+1) DMA issued right after bar1(j) (ph1 reads done), drains by
//     bar2(j) -> no cold ph0 stall per tile
//   - phase bodies (ph1/ph2/ph3/reduce/store) are v6-verbatim
// Tail-roll safety: waves 4-7 enter ph1(j+1) after bar4(j); all DMAs drained
// at bar2(j); reduce readers (waves 0-3, Pr) vs ph1 readers (Ls) disjoint;
// ph2(j+1) gated by bar1(j+1).
// ---------------------------------------------------------------------------
__global__ __launch_bounds__(512, 2)
void fuse_kernel(const f16* __restrict__ left_t, const f16* __restrict__ rt2,
                 const f16* __restrict__ wt2, float* __restrict__ out) {
    extern __shared__ __align__(16) char lds[];
    f16* Ls = (f16*)lds;                 // 64KB left tile
    char* Pr = lds + 65536;              // 64KB pair tile / reduce buffer

    int b = blockIdx.x;                  // 256 = 8 xcd * 32
    int vb = (b & 7) * 32 + (b >> 3);    // bijective XCD chunking
    int brq = vb >> 6, bt = vb & 63;     // brq in [0,4), bt in [0,64)
    int tid = threadIdx.x;
    int w = tid >> 6, lane = tid & 63;
    int q5 = lane >> 5, l31 = lane & 31, lx = lane & 15;

    int t_tile = w & 3, rg4 = w >> 2;    // ph1 wave map
    int kh = w >> 2;                     // ph3 wave map (ntile == t_tile)
    int chc = l31 >> 1, bsub = 8 * (l31 & 1);

    // ---- prologue: DMA left(j=0); afr + wR resident loads ----
    {
        const f16* Lg = left_t + (size_t)(brq * 8) * 32768;
#pragma unroll
        for (int it = 0; it < 8; it++)
            GLOAD_LDS16(Lg + (size_t)(it * 512 + tid) * 8, Ls + (it * 512 + tid) * 8);
    }
    const f16* ap = rt2 + (size_t)(bt * 4 + t_tile) * 4096 + (l31 * 2 + q5) * 8;
    f16x8 afr[8];
#pragma unroll
    for (int ks = 0; ks < 8; ks++) afr[ks] = *(const f16x8*)(ap + ks * 512);

    const f16* wbase = wt2 + (size_t)(t_tile * 64 + kh * 32) * 512 + (l31 * 2 + q5) * 8;
    f16x8 wR[8];                         // W chunks 0..7 resident (gg=0,1)
#pragma unroll
    for (int c = 0; c < 8; c++) wR[c] = *(const f16x8*)(wbase + c * 512);

    const char* lbase = Pr + l31 * 2048;
    int base = 64 * kh + q5 + l31;

    __syncthreads();   // bar0: prologue DMA + loads drained

#pragma unroll 1
    for (int j = 0; j < 8; j++) {
        int br = brq * 8 + j;

        // ---- phase 1: stage1 MFMAs (left LDS x resident afr) ----
        f32x16 acc[4] = {};
        __builtin_amdgcn_s_setprio(1);
#pragma unroll
        for (int i = 0; i < 4; i++) {
            const f16* bbase = Ls + ((rg4 * 4 + i) * 32 + l31) * 128;
#pragma unroll
            for (int ks = 0; ks < 8; ks++) {
                f16x8 bfr = *(const f16x8*)(bbase + (((2 * ks + q5) ^ lx) << 3));
                acc[i] = __builtin_amdgcn_mfma_f32_32x32x16_f16(afr[ks], bfr, acc[i], 0, 0, 0);
            }
        }
        __builtin_amdgcn_s_setprio(0);
        __syncthreads();   // bar1: left reads done -> Ls free

        // ---- DMA left(j+1): drains at bar2, hidden under ph2 ----
        if (j < 7) {
            const f16* Lg = left_t + (size_t)(br + 1) * 32768;
#pragma unroll
            for (int it = 0; it < 8; it++)
                GLOAD_LDS16(Lg + (size_t)(it * 512 + tid) * 8, Ls + (it * 512 + tid) * 8);
        }

        // ---- phase 2: write outer to pair tile ----
#pragma unroll
        for (int i = 0; i < 4; i++) {
            int p = (rg4 * 4 + i) * 4 + t_tile;         // pair row 0..31
            char* prow = Pr + p * 2048;
#pragma unroll
            for (int rg = 0; rg < 4; rg++) {
                int ch = (2 * rg + q5) * 16 + chc;
                int phys = (ch + p) & 127;
                f16x4 h = {(f16)acc[i][4 * rg], (f16)acc[i][4 * rg + 1],
                           (f16)acc[i][4 * rg + 2], (f16)acc[i][4 * rg + 3]};
                *(f16x4*)(prow + phys * 16 + bsub) = h;
            }
        }
        __syncthreads();   // bar2: pair ready; DMA(j+1) drained

        // ---- phase 3: stage2. W: gg 0,1 from wR; gg 2..7 streamed lead-3 ----
        f16x8 wfs[8][4];   // slots 2..7 used; compile-time indices after unroll
#pragma unroll
        for (int u = 0; u < 4; u++) wfs[2][u] = *(const f16x8*)(wbase + (8 + u) * 512);
#pragma unroll
        for (int u = 0; u < 4; u++) wfs[3][u] = *(const f16x8*)(wbase + (12 + u) * 512);
        f16x8 afg[8][4];
#pragma unroll
        for (int u = 0; u < 4; u++)
            afg[0][u] = *(const f16x8*)(lbase + (((base + 2 * u) & 127) << 4));
#pragma unroll
        for (int u = 0; u < 4; u++)
            afg[1][u] = *(const f16x8*)(lbase + (((base + 8 + 2 * u) & 127) << 4));

        f32x16 accA = {}, accB = {};
        __builtin_amdgcn_s_setprio(1);
#pragma unroll
        for (int gg = 0; gg < 8; gg++) {
            if (gg == 1 || gg == 2 || gg == 3) {
                int s = gg + 3;                          // stream groups 4,5,6
#pragma unroll
                for (int u = 0; u < 4; u++)
                    wfs[s][u] = *(const f16x8*)(wbase + (s * 4 + u) * 512);
            }
            if (gg == 5) {
#pragma unroll
                for (int u = 0; u < 4; u++)
                    wfs[7][u] = *(const f16x8*)(wbase + (28 + u) * 512);
            }
            if (gg >= 1 && gg + 1 < 8) {
#pragma unroll
                for (int u = 0; u < 4; u++)
                    afg[gg + 1][u] = *(const f16x8*)(lbase + (((base + (gg + 1) * 8 + 2 * u) & 127) << 4));
            }
            if (gg == 0) {
                accA = __builtin_amdgcn_mfma_f32_32x32x16_f16(afg[gg][0], wR[0], accA, 0, 0, 0);
                accB = __builtin_amdgcn_mfma_f32_32x32x16_f16(afg[gg][1], wR[1], accB, 0, 0, 0);
                accA = __builtin_amdgcn_mfma_f32_32x32x16_f16(afg[gg][2], wR[2], accA, 0, 0, 0);
                accB = __builtin_amdgcn_mfma_f32_32x32x16_f16(afg[gg][3], wR[3], accB, 0, 0, 0);
            } else if (gg == 1) {
                accA = __builtin_amdgcn_mfma_f32_32x32x16_f16(afg[gg][0], wR[4], accA, 0, 0, 0);
                accB = __builtin_amdgcn_mfma_f32_32x32x16_f16(afg[gg][1], wR[5], accB, 0, 0, 0);
                accA = __builtin_amdgcn_mfma_f32_32x32x16_f16(afg[gg][2], wR[6], accA, 0, 0, 0);
                accB = __builtin_amdgcn_mfma_f32_32x32x16_f16(afg[gg][3], wR[7], accB, 0, 0, 0);
            } else {
                accA = __builtin_amdgcn_mfma_f32_32x32x16_f16(afg[gg][0], wfs[gg][0], accA, 0, 0, 0);
                accB = __builtin_amdgcn_mfma_f32_32x32x16_f16(afg[gg][1], wfs[gg][1], accB, 0, 0, 0);
                accA = __builtin_amdgcn_mfma_f32_32x32x16_f16(afg[gg][2], wfs[gg][2], accA, 0, 0, 0);
                accB = __builtin_amdgcn_mfma_f32_32x32x16_f16(afg[gg][3], wfs[gg][3], accB, 0, 0, 0);
            }
        }
        __builtin_amdgcn_s_setprio(0);
        f32x16 acc2;
#pragma unroll
        for (int v = 0; v < 16; v++) acc2[v] = accA[v] + accB[v];
        __syncthreads();   // bar3: pair reads done

        // ---- k-reduction: wave w+4 -> Pr, wave w adds ----
        if (w >= 4) {
            char* rb = Pr + (w - 4) * 4096 + lane * 64;
#pragma unroll
            for (int u = 0; u < 4; u++) {
                f32x4 part = {acc2[4 * u], acc2[4 * u + 1], acc2[4 * u + 2], acc2[4 * u + 3]};
                *(f32x4*)(rb + u * 16) = part;
            }
        }
        __syncthreads();   // bar4
        if (w < 4) {
            const char* rb = Pr + w * 4096 + lane * 64;
#pragma unroll
            for (int u = 0; u < 4; u++) {
                f32x4 part = *(const f32x4*)(rb + u * 16);
#pragma unroll
                for (int v = 0; v < 4; v++) acc2[4 * u + v] += part[v];
            }
            // store: D row = p = (reg&3)+8*(reg>>2)+4*q5 ; col = cz = w*32 + l31
            int r0 = br * 8, t0 = bt * 4, cz = w * 32 + l31;
#pragma unroll
            for (int reg = 0; reg < 16; reg++) {
                int p = (reg & 3) + 8 * (reg >> 2) + 4 * q5;
                out[((size_t)((r0 + (p >> 2)) * R_DIM + t0 + (p & 3))) * CZ_DIM + cz] = acc2[reg];
            }
        }
        // waves 4-7 roll into ph1(j+1): Ls fully staged (all DMAs drained at
        // bar2); Pr reduce-readers protected by bar1(j+1).
    }
}

// ---------------------------------------------------------------------------
extern "C" void kernel_launch(void* const* d_in, const int* in_sizes, int n_in,
                              void* d_out, int out_size, void* d_ws, size_t ws_size,
                              hipStream_t stream) {
    const float* msa = (const float*)d_in[0];
    const float* lw  = (const float*)d_in[1];
    const float* rw  = (const float*)d_in[2];
    const float* ow  = (const float*)d_in[3];
    char* ws = (char*)d_ws;
    f16* left_t = (f16*)(ws);                                   // 2 MB (pre-swizzled)
    f16* rt2    = (f16*)(ws + (size_t)2 * 1024 * 1024);         // 2 MB
    f16* wt2    = (f16*)(ws + (size_t)4 * 1024 * 1024);         // 256 KB
    float* out  = (float*)d_out;

    static bool attr_set = false;
    if (!attr_set) {
        hipFuncSetAttribute((const void*)fuse_kernel,
                            hipFuncAttributeMaxDynamicSharedMemorySize, 131072);
        attr_set = true;
    }

    proj_kernel<<<dim3(512), dim3(256), 0, stream>>>(msa, lw, rw, ow, left_t, rt2, wt2);
    fuse_kernel<<<dim3(256), dim3(512), 131072, stream>>>(left_t, rt2, wt2, out);
}

// Round 7
// 134.019 us; speedup vs baseline: 1.1311x; 1.1311x over previous
//
#include <hip/hip_runtime.h>
#include <stdint.h>

// Dims: msa[1,S,R,M] fp32 ; left_w/right_w[M,C] ; out_w[C*C,CZ] ; out[1,R,R,CZ] fp32
#define S_DIM 128
#define R_DIM 256
#define M_DIM 256
#define C_DIM 32
#define CZ_DIM 128
#define K2_DIM 1024  // C*C

typedef _Float16 f16;
typedef _Float16 f16x4 __attribute__((ext_vector_type(4)));
typedef _Float16 f16x8 __attribute__((ext_vector_type(8)));
typedef float f32x4 __attribute__((ext_vector_type(4)));
typedef float f32x16 __attribute__((ext_vector_type(16)));

typedef const __attribute__((address_space(1))) uint32_t gu32_t;
typedef __attribute__((address_space(3))) uint32_t lu32_t;
// async 16B global->LDS DMA; LDS dest = wave-uniform base + lane*16 (linear)
#define GLOAD_LDS16(g, l) \
    __builtin_amdgcn_global_load_lds((gu32_t*)(g), (lu32_t*)(l), 16, 0, 0)

// ---------------------------------------------------------------------------
// proj v2: R1 body + LDS-bounce coalesced epilogue.
// Old epilogue: 16 scalar 2-B global scatter stores per thread (~25% line
// utilization). New: stage the block's 8 KB output image in LDS, then emit
// 512 x 16-B fully-coalesced stores (left: 32 x 128 B contiguous half-rows;
// rt2: 4 x 1 KB contiguous chunks). Decomposition (verified):
//   left f16 off = row0*128 + swz*8 + sj = row0*128 + H*64 + o,
//   H = ((c0&8)>>3)^(s0>>6) (block-constant per row), o = ((sc^c0)&7)*8+sj.
// ---------------------------------------------------------------------------
__global__ __launch_bounds__(256, 4)
void proj_kernel(const float* __restrict__ msa, const float* __restrict__ lw,
                 const float* __restrict__ rw, const float* __restrict__ ow,
                 f16* __restrict__ left_t, f16* __restrict__ rt2,
                 f16* __restrict__ wt2) {
    __shared__ __align__(16) f16 wlT[8192];  // [mc][c][j]; reused as bounce buf
    __shared__ __align__(16) f16 wrT[8192];

    int bid = blockIdx.x;            // 512 = 256 r * 2 s-halves
    int tid = threadIdx.x;
    int w = tid >> 6;
    int lane = tid & 63;
    int q = lane >> 4, li = lane & 15;
    int r  = bid >> 1;
    int s0 = (bid & 1) << 6;
    int s_col = s0 + w * 16 + li;

    // issue msa loads first — latency hides under stage A
    const f32x4* bp = (const f32x4*)(msa + ((size_t)s_col * R_DIM + r) * M_DIM + q * 8);
    f32x4 b[16];
#pragma unroll
    for (int ks = 0; ks < 8; ks++) { b[2 * ks] = bp[ks * 8]; b[2 * ks + 1] = bp[ks * 8 + 1]; }

    // ---- stage A: wt2 slice (one element per thread across grid) ----
    {
        int i = bid * 256 + tid;     // in [0, CZ*K2)
        int cz = i >> 10, k2 = i & 1023;
        int c = k2 >> 5, e = k2 & 31;
        int k2p = ((e >> 2) << 7) + (c << 2) + (e & 3);
        int ntile = cz >> 5, l31o = cz & 31;
        int kk = k2p >> 4, q5o = (k2p >> 3) & 1, j = k2p & 7;
        wt2[(ntile * 64 + kk) * 512 + (l31o * 2 + q5o) * 8 + j] = (f16)ow[k2 * CZ_DIM + cz];
    }
    // ---- stage A: weight transpose-stage (coalesced fp32 reads) ----
#pragma unroll
    for (int k = 0; k < 32; k++) {
        int i = k * 256 + tid;       // i = m*32 + c
        int m = i >> 5, c = i & 31;
        int d = ((m >> 3) * 32 + c) * 8 + (m & 7);
        wlT[d] = (f16)lw[i];
        wrT[d] = (f16)rw[i];
    }
    __syncthreads();

    // ---- stage B: MFMA loop, frags from LDS ----
    f32x4 aL0 = {0,0,0,0}, aL1 = {0,0,0,0}, aR0 = {0,0,0,0}, aR1 = {0,0,0,0};
#pragma unroll
    for (int ks = 0; ks < 8; ks++) {
        f16x8 bf;
#pragma unroll
        for (int u = 0; u < 4; u++) { bf[u] = (f16)b[2*ks][u]; bf[4 + u] = (f16)b[2*ks+1][u]; }
        const f16* a0 = wlT + ((ks * 4 + q) * 32 + li) * 8;
        const f16* a1 = wrT + ((ks * 4 + q) * 32 + li) * 8;
        f16x8 al0 = *(const f16x8*)(a0);
        f16x8 al1 = *(const f16x8*)(a0 + 128);   // rows li+16
        f16x8 ar0 = *(const f16x8*)(a1);
        f16x8 ar1 = *(const f16x8*)(a1 + 128);
        aL0 = __builtin_amdgcn_mfma_f32_16x16x32_f16(al0, bf, aL0, 0, 0, 0);
        aL1 = __builtin_amdgcn_mfma_f32_16x16x32_f16(al1, bf, aL1, 0, 0, 0);
        aR0 = __builtin_amdgcn_mfma_f32_16x16x32_f16(ar0, bf, aR0, 0, 0, 0);
        aR1 = __builtin_amdgcn_mfma_f32_16x16x32_f16(ar1, bf, aR1, 0, 0, 0);
    }

    __syncthreads();   // weight reads done -> reuse wlT as bounce buffer
    f16* bL = wlT;               // [32 rows][64] f16 = 4 KB (block's left image)
    f16* bR = wlT + 2048;        // [4 kl][512] f16 = 4 KB (block's rt2 image)
    {
        int sc7 = (s_col >> 3) & 7, sj = s_col & 7;
        int kl = (s_col >> 4) & 3;             // ks_s - (s0>>4)
        int q5_s = (s_col >> 3) & 1;
#pragma unroll
        for (int reg = 0; reg < 4; reg++) {
            int c0 = q * 4 + reg;              // 0..15
            int o = ((sc7 ^ c0) & 7) * 8 + sj;
            bL[c0 * 64 + o]        = (f16)aL0[reg];
            bL[(c0 + 16) * 64 + o] = (f16)aL1[reg];
            bR[kl * 512 + c0 * 16 + q5_s * 8 + sj]        = (f16)aR0[reg];
            bR[kl * 512 + (c0 + 16) * 16 + q5_s * 8 + sj] = (f16)aR1[reg];
        }
    }
    __syncthreads();   // bounce images complete

    // ---- coalesced stores: 256 threads x (16 B left + 16 B rt2) ----
    {
        int sH = s0 >> 6;                       // 0 | 1
        int lr = tid >> 3;                      // 0..31
        int H = ((lr & 8) >> 3) ^ sH;
        f16* Lb = left_t + (size_t)(r >> 3) * 32768;
        *(f16x8*)(Lb + ((r & 7) * 32 + lr) * 128 + H * 64 + (tid & 7) * 8) =
            *(const f16x8*)(bL + lr * 64 + (tid & 7) * 8);

        int kl2 = tid >> 6, ix = tid & 63;      // 4 chunks x 1 KB
        *(f16x8*)(rt2 + (size_t)(r * 8 + (s0 >> 4) + kl2) * 512 + ix * 8) =
            *(const f16x8*)(bR + kl2 * 512 + ix * 8);
    }
}

// ---------------------------------------------------------------------------
// fuse_kernel v8 (R4-proven best, verbatim): v6 body + bijective XCD swizzle
// + setprio around MFMA clusters. 2 blocks/CU, 64 KB LDS overlay, ~124 regs.
// Register wall documented (v7/v9/v10 all spilled) — do not add residency.
// ---------------------------------------------------------------------------
__global__ __launch_bounds__(512, 4)
void fuse_kernel(const f16* __restrict__ left_t, const f16* __restrict__ rt2,
                 const f16* __restrict__ wt2, float* __restrict__ out) {
    __shared__ __align__(16) char lds[65536];
    f16* Ls = (f16*)lds;

    // XCD swizzle (bijective: 2048 = 8*256): XCD x gets vbid [x*256,(x+1)*256)
    int bid0 = blockIdx.x;
    int bid = (bid0 & 7) * 256 + (bid0 >> 3);
    int br = bid >> 6, bt = bid & 63;
    int tid = threadIdx.x;
    int w = tid >> 6, lane = tid & 63;
    int q5 = lane >> 5, l31 = lane & 31, lx = lane & 15;

    const f16* Lg = left_t + (size_t)br * 32768;    // pre-swizzled LDS image

    // ---- phase 0: async stage left (8 x 16B DMA per thread) ----
#pragma unroll
    for (int it = 0; it < 8; it++) {
        GLOAD_LDS16(Lg + (size_t)(it * 512 + tid) * 8, Ls + (it * 512 + tid) * 8);
    }

    // afr prefetch (coalesced fragment-major) — overlaps the DMA
    int t_tile = w & 3, rg4 = w >> 2;
    int g = bt * 4 + t_tile;
    const f16* ap = rt2 + (size_t)g * 4096 + (l31 * 2 + q5) * 8;
    f16x8 afr[8];
#pragma unroll
    for (int ks = 0; ks < 8; ks++) afr[ks] = *(const f16x8*)(ap + ks * 512);

    __syncthreads();   // drains vmcnt → LDS stage complete

    // ---- phase 1: stage1 MFMAs (D[te][rc]) ----
    f32x16 acc[4] = {};
    __builtin_amdgcn_s_setprio(1);
#pragma unroll
    for (int i = 0; i < 4; i++) {
        const f16* bbase = Ls + ((rg4 * 4 + i) * 32 + l31) * 128;
#pragma unroll
        for (int ks = 0; ks < 8; ks++) {
            f16x8 bfr = *(const f16x8*)(bbase + (((2 * ks + q5) ^ lx) << 3));
            acc[i] = __builtin_amdgcn_mfma_f32_32x32x16_f16(afr[ks], bfr, acc[i], 0, 0, 0);
        }
    }
    __builtin_amdgcn_s_setprio(0);

    // ---- W group 0: issue pre-barrier (hidden by phase 2 + barrier) ----
    int ntile = w & 3, kh = w >> 2;
    const f16* wbase = wt2 + (size_t)(ntile * 64 + kh * 32) * 512 + (l31 * 2 + q5) * 8;
    f16x8 wfg[8][4];
#pragma unroll
    for (int u = 0; u < 4; u++) wfg[0][u] = *(const f16x8*)(wbase + u * 512);

    __syncthreads();   // protects LDS overlay (phase2 writes over Ls)

    // ---- phase 2: write outer to LDS ----
    int chc = l31 >> 1, bsub = 8 * (l31 & 1);
#pragma unroll
    for (int i = 0; i < 4; i++) {
        int p = (rg4 * 4 + i) * 4 + t_tile;         // pair row 0..31
        char* prow = lds + p * 2048;
#pragma unroll
        for (int rg = 0; rg < 4; rg++) {
            int ch = (2 * rg + q5) * 16 + chc;
            int phys = (ch + p) & 127;
            f16x4 h = {(f16)acc[i][4 * rg], (f16)acc[i][4 * rg + 1],
                       (f16)acc[i][4 * rg + 2], (f16)acc[i][4 * rg + 3]};
            *(f16x4*)(prow + phys * 16 + bsub) = h;
        }
    }
    __syncthreads();

    // ---- phase 3: stage2, fully unrolled, 3-deep W ring + 2-deep af ring ----
    const char* lbase = lds + l31 * 2048;           // p = l31 (2048-aligned rows)
    int base = 64 * kh + q5 + l31;                  // k-chunk index before wrap
    f16x8 afg[8][4];
    f32x16 accA = {}, accB = {};
    __builtin_amdgcn_s_setprio(1);
#pragma unroll
    for (int gg = 0; gg < 8; gg++) {
        if (gg == 0) {
            // fill rings: W groups 1,2 ; af groups 0,1
#pragma unroll
            for (int u = 0; u < 4; u++) wfg[1][u] = *(const f16x8*)(wbase + (4 + u) * 512);
#pragma unroll
            for (int u = 0; u < 4; u++) wfg[2][u] = *(const f16x8*)(wbase + (8 + u) * 512);
#pragma unroll
            for (int u = 0; u < 4; u++)
                afg[0][u] = *(const f16x8*)(lbase + (((base + 2 * u) & 127) << 4));
#pragma unroll
            for (int u = 0; u < 4; u++)
                afg[1][u] = *(const f16x8*)(lbase + (((base + 8 + 2 * u) & 127) << 4));
        } else {
            if (gg + 2 < 8) {
#pragma unroll
                for (int u = 0; u < 4; u++)
                    wfg[gg + 2][u] = *(const f16x8*)(wbase + ((gg + 2) * 4 + u) * 512);
            }
            if (gg + 1 < 8) {
#pragma unroll
                for (int u = 0; u < 4; u++)
                    afg[gg + 1][u] = *(const f16x8*)(lbase + (((base + (gg + 1) * 8 + 2 * u) & 127) << 4));
            }
        }
        accA = __builtin_amdgcn_mfma_f32_32x32x16_f16(afg[gg][0], wfg[gg][0], accA, 0, 0, 0);
        accB = __builtin_amdgcn_mfma_f32_32x32x16_f16(afg[gg][1], wfg[gg][1], accB, 0, 0, 0);
        accA = __builtin_amdgcn_mfma_f32_32x32x16_f16(afg[gg][2], wfg[gg][2], accA, 0, 0, 0);
        accB = __builtin_amdgcn_mfma_f32_32x32x16_f16(afg[gg][3], wfg[gg][3], accB, 0, 0, 0);
    }
    __builtin_amdgcn_s_setprio(0);
    f32x16 acc2;
#pragma unroll
    for (int v = 0; v < 16; v++) acc2[v] = accA[v] + accB[v];
    __syncthreads();

    // ---- k-reduction: wave w+4 -> LDS, wave w adds ----
    if (w >= 4) {
        char* rb = lds + (w - 4) * 4096 + lane * 64;
#pragma unroll
        for (int u = 0; u < 4; u++) {
            f32x4 part = {acc2[4 * u], acc2[4 * u + 1], acc2[4 * u + 2], acc2[4 * u + 3]};
            *(f32x4*)(rb + u * 16) = part;
        }
    }
    __syncthreads();
    if (w < 4) {
        const char* rb = lds + w * 4096 + lane * 64;
#pragma unroll
        for (int u = 0; u < 4; u++) {
            f32x4 part = *(const f32x4*)(rb + u * 16);
#pragma unroll
            for (int v = 0; v < 4; v++) acc2[4 * u + v] += part[v];
        }
        // store: D row = p = (reg&3)+8*(reg>>2)+4*q5 ; col = cz = w*32 + l31
        int r0 = br * 8, t0 = bt * 4, cz = w * 32 + l31;
#pragma unroll
        for (int reg = 0; reg < 16; reg++) {
            int p = (reg & 3) + 8 * (reg >> 2) + 4 * q5;
            out[((size_t)((r0 + (p >> 2)) * R_DIM + t0 + (p & 3))) * CZ_DIM + cz] = acc2[reg];
        }
    }
}

// ---------------------------------------------------------------------------
extern "C" void kernel_launch(void* const* d_in, const int* in_sizes, int n_in,
                              void* d_out, int out_size, void* d_ws, size_t ws_size,
                              hipStream_t stream) {
    const float* msa = (const float*)d_in[0];
    const float* lw  = (const float*)d_in[1];
    const float* rw  = (const float*)d_in[2];
    const float* ow  = (const float*)d_in[3];
    char* ws = (char*)d_ws;
    f16* left_t = (f16*)(ws);                                   // 2 MB (pre-swizzled)
    f16* rt2    = (f16*)(ws + (size_t)2 * 1024 * 1024);         // 2 MB
    f16* wt2    = (f16*)(ws + (size_t)4 * 1024 * 1024);         // 256 KB
    float* out  = (float*)d_out;

    proj_kernel<<<dim3(512), dim3(256), 0, stream>>>(msa, lw, rw, ow, left_t, rt2, wt2);
    fuse_kernel<<<dim3(2048), dim3(512), 0, stream>>>(left_t, rt2, wt2, out);
}